// Round 2
// baseline (142676.099 us; speedup 1.0000x reference)
//
#include <hip/hip_runtime.h>
#include <stdint.h>

typedef unsigned int u32;
typedef unsigned long long u64;
typedef unsigned short u16;
typedef __attribute__((ext_vector_type(8))) short bf16x8;
typedef __attribute__((ext_vector_type(4))) float f32x4;
typedef __attribute__((ext_vector_type(4))) u16 u16x4;

// Problem constants
#define T_STEPS 512
#define BATCH   64
#define IDIM    512
#define HDIM    1024
#define GDIM    4096   // 4*H
#define KDIM    1536   // I+H
#define NWG     256    // 8 batch-groups x 32 h-shards, 1 WG/CU (proven chassis)
#define NGRP    8
#define NSHARD  32

// ws layout (bytes)
#define GB_OFF  0u                    // Gx bf16 [32768][4096]  = 268435456
#define XB_OFF  268435456u            // X bf16  [32768][512]   = 33554432
#define WX_OFF  301989888u            // Wx bf16 [4096][512]    = 4194304
#define HX_OFF  306184192u            // hx bf16 [2][64][1024]  = 262144
// Barrier flags + rendezvous ctrl overlay the Xb region (dead after k_gemm_gx).
#define ARR_OFF XB_OFF                // 256 flag slots x 64B + ctrl

__device__ __forceinline__ u16 f2bf(float f) {
  union { float f; u32 u; } v; v.f = f;
  return (u16)((v.u + 0x7fffu + ((v.u >> 16) & 1u)) >> 16);   // RNE
}
__device__ __forceinline__ float bf2f(u16 h) {
  union { u32 u; float f; } v; v.u = ((u32)h) << 16; return v.f;
}

#define GLDS(g, l) __builtin_amdgcn_global_load_lds( \
    (const __attribute__((address_space(1))) u32*)(g), \
    (__attribute__((address_space(3))) u32*)(l), 16, 0, 0)

// ---------------- Phase A: conversions / init ----------------
__global__ void k_cvt4(const float* __restrict__ src, u16* __restrict__ dst, int n4) {
  int i = blockIdx.x * blockDim.x + threadIdx.x;
  int stride = gridDim.x * blockDim.x;
  for (; i < n4; i += stride) {
    float4 v = reinterpret_cast<const float4*>(src)[i];
    u16x4 o; o.x = f2bf(v.x); o.y = f2bf(v.y); o.z = f2bf(v.z); o.w = f2bf(v.w);
    reinterpret_cast<u16x4*>(dst)[i] = o;
  }
}

__global__ void k_cvt_wx(const float* __restrict__ W, u16* __restrict__ wxb) {
  int i = blockIdx.x * blockDim.x + threadIdx.x;   // over 4096*128 float4 groups
  if (i >= GDIM * (IDIM / 4)) return;
  int row = i >> 7, cg = i & 127;
  float4 v = *reinterpret_cast<const float4*>(W + (size_t)row * KDIM + cg * 4);
  u16x4 o; o.x = f2bf(v.x); o.y = f2bf(v.y); o.z = f2bf(v.z); o.w = f2bf(v.w);
  *reinterpret_cast<u16x4*>(wxb + (size_t)row * IDIM + cg * 4) = o;
}

__global__ void k_zero(u32* __restrict__ p, int n) {
  int i = blockIdx.x * blockDim.x + threadIdx.x;
  int stride = gridDim.x * blockDim.x;
  for (; i < n; i += stride) p[i] = 0u;
}

// ---------------- Phase B: Gx = Xbf16 @ Wx^T + b (bf16 out) ----------------
// M=32768, N=4096, K=512. 128x128 tile, BK=64, 4 waves each 64x64.
__global__ void k_gemm_gx(const u16* __restrict__ Xb, const u16* __restrict__ Wxb,
                          const float* __restrict__ bias, u16* __restrict__ Gb) {
  __shared__ u16 lA[128 * 64];
  __shared__ u16 lB[128 * 64];
  const int tid = threadIdx.x;
  const int wv = tid >> 6, l = tid & 63;
  const int ln = l & 15, lg = l >> 4;
  const int m0 = blockIdx.x * 128, n0 = blockIdx.y * 128;
  const int wr = wv >> 1, wc = wv & 1;

  f32x4 acc[4][4];
  #pragma unroll
  for (int mi = 0; mi < 4; ++mi)
    #pragma unroll
    for (int nj = 0; nj < 4; ++nj) acc[mi][nj] = (f32x4){0.f, 0.f, 0.f, 0.f};

  for (int kt = 0; kt < 8; ++kt) {
    #pragma unroll
    for (int it = 0; it < 4; ++it) {
      int off = it * 4096 + tid * 16;      // byte offset in 16KB tile
      int row = off >> 7;                  // 128 B per row (64 bf16)
      int col = (off & 127) >> 1;          // bf16 col
      GLDS(Xb  + (size_t)(m0 + row) * IDIM + kt * 64 + col, (char*)lA + off);
      GLDS(Wxb + (size_t)(n0 + row) * IDIM + kt * 64 + col, (char*)lB + off);
    }
    asm volatile("s_waitcnt vmcnt(0)" ::: "memory");
    __syncthreads();
    #pragma unroll
    for (int ks = 0; ks < 2; ++ks) {
      bf16x8 af[4], bfr[4];
      #pragma unroll
      for (int mi = 0; mi < 4; ++mi)
        af[mi] = *reinterpret_cast<const bf16x8*>(&lA[(wr * 64 + mi * 16 + ln) * 64 + ks * 32 + lg * 8]);
      #pragma unroll
      for (int nj = 0; nj < 4; ++nj)
        bfr[nj] = *reinterpret_cast<const bf16x8*>(&lB[(wc * 64 + nj * 16 + ln) * 64 + ks * 32 + lg * 8]);
      #pragma unroll
      for (int mi = 0; mi < 4; ++mi)
        #pragma unroll
        for (int nj = 0; nj < 4; ++nj)
          acc[mi][nj] = __builtin_amdgcn_mfma_f32_16x16x32_bf16(af[mi], bfr[nj], acc[mi][nj], 0, 0, 0);
    }
    __syncthreads();
  }
  float bv[4];
  #pragma unroll
  for (int nj = 0; nj < 4; ++nj) bv[nj] = bias[n0 + wc * 64 + nj * 16 + ln];
  #pragma unroll
  for (int mi = 0; mi < 4; ++mi)
    #pragma unroll
    for (int r = 0; r < 4; ++r) {
      int m = m0 + wr * 64 + mi * 16 + lg * 4 + r;
      #pragma unroll
      for (int nj = 0; nj < 4; ++nj)
        Gb[(size_t)m * GDIM + n0 + wc * 64 + nj * 16 + ln] = f2bf(acc[mi][nj][r] + bv[nj]);
    }
}

// ---------------- Phase C: persistent recurrent kernel ----------------
// 256 WGs = 8 batch-groups(g = w&7: 8 rows) x 32 h-shards(j = w>>3: 32 h).
// 1 WG/CU (co-residency proven by the 2940us baseline). Under the round-robin
// blockIdx->XCD mapping, g = w&7 makes each group XCD-pure; purity is VERIFIED
// at runtime (full-evidence HW_REG_XCC_ID mask). Pure groups exchange h via
// their shared per-XCD L2 (sc0-only, ~3x lower latency than L3); impure groups
// fall back to the proven device-scope (sc0 sc1) protocol. All spins are
// bounded or escalate: no placement outcome can hang.
template<bool PURE>
__device__ __forceinline__ void lstm_run(
    const u16* __restrict__ Gb, u16* __restrict__ hxb,
    u32* __restrict__ flags, float* __restrict__ out,
    f32x4* As, bf16x8 (&w0)[32], bf16x8 (&w1)[32],
    int g, int j, int tid, int jcol0, int jcol1)
{
  const int wv = tid >> 6, l = tid & 63;
  const int n = l & 15, lg = l >> 4;
  const int h0w = j * 32 + wv * 8;               // this wave's 8 h-cols
  const int srow = tid & 7, sseg = tid >> 3;     // A-staging mapping (8 rows x 32 segs)

  float cx[4] = {0.f, 0.f, 0.f, 0.f};

  #pragma unroll 1
  for (int t = 0; t < T_STEPS; ++t) {
    // issue Gx loads early (plain loads; latency hides under poll+stage)
    u16 ga[4] = {0, 0, 0, 0}, gb_[4] = {0, 0, 0, 0};
    if (lg < 2) {
      #pragma unroll
      for (int r = 0; r < 4; ++r) {
        int ba = g * 8 + lg * 4 + r;
        const u16* gp = Gb + ((size_t)t * BATCH + ba) * GDIM;
        ga[r]  = gp[jcol0];
        gb_[r] = gp[jcol1];
      }
    }

    // group-local barrier: half-wave polls the group's 32 flags
    if (t > 0) {
      if (tid < NSHARD) {
        u32* slot = flags + (g * NSHARD + tid) * 16;
        u32 v, tries = 0;
        while (1) {
          if (PURE && tries < 2048u) {
            asm volatile("global_load_dword %0, %1, off sc0\n\ts_waitcnt vmcnt(0)"
                         : "=&v"(v) : "v"(slot) : "memory");
          } else {
            // escalation / slow path: device-scope (sees the sc1 flag copy)
            v = __hip_atomic_load(slot, __ATOMIC_RELAXED, __HIP_MEMORY_SCOPE_AGENT);
          }
          if (v >= (u32)t) break;
          ++tries;
          __builtin_amdgcn_s_sleep(1);
        }
      }
      __syncthreads();
    }

    // A-stage: 8 rows x 1024 h (16 KB) -> LDS fragment order (rows 8..15 stay 0)
    const u16* asrc = hxb + (size_t)(t & 1) * (BATCH * HDIM)
                    + (size_t)(g * 8 + srow) * HDIM + sseg * 32;
    f32x4 ld[4];
    #pragma unroll
    for (int q = 0; q < 4; ++q) {
      if (PURE)
        asm volatile("global_load_dwordx4 %0, %1, off sc0"
                     : "=&v"(ld[q]) : "v"(asrc + q * 8) : "memory");
      else
        asm volatile("global_load_dwordx4 %0, %1, off sc0 sc1"
                     : "=&v"(ld[q]) : "v"(asrc + q * 8) : "memory");
    }
    asm volatile("s_waitcnt vmcnt(0)" ::: "memory");
    __builtin_amdgcn_sched_barrier(0);
    #pragma unroll
    for (int q = 0; q < 4; ++q)
      As[sseg * 64 + q * 16 + srow] = ld[q];   // As[ks][lg][row]
    __syncthreads();

    // gates = Gx + hx @ Wh^T : 2 N-tiles x 32 ks, 4 independent MFMA chains
    f32x4 c00 = {bf2f(ga[0]),  bf2f(ga[1]),  bf2f(ga[2]),  bf2f(ga[3])};
    f32x4 c10 = {bf2f(gb_[0]), bf2f(gb_[1]), bf2f(gb_[2]), bf2f(gb_[3])};
    f32x4 c01 = {0.f, 0.f, 0.f, 0.f}, c11 = c01;
    #pragma unroll
    for (int ks = 0; ks < 32; ks += 2) {
      bf16x8 f0 = *reinterpret_cast<const bf16x8*>(&As[(ks + 0) * 64 + l]);
      bf16x8 f1 = *reinterpret_cast<const bf16x8*>(&As[(ks + 1) * 64 + l]);
      c00 = __builtin_amdgcn_mfma_f32_16x16x32_bf16(f0, w0[ks + 0], c00, 0, 0, 0);
      c10 = __builtin_amdgcn_mfma_f32_16x16x32_bf16(f0, w1[ks + 0], c10, 0, 0, 0);
      c01 = __builtin_amdgcn_mfma_f32_16x16x32_bf16(f1, w0[ks + 1], c01, 0, 0, 0);
      c11 = __builtin_amdgcn_mfma_f32_16x16x32_bf16(f1, w1[ks + 1], c11, 0, 0, 0);
    }
    f32x4 t0 = c00 + c01, t1 = c10 + c11;

    // elementwise. tile0: n<8 -> f, n>=8 -> i. tile1: n<8 -> g(tanh), n>=8 -> o.
    u16* hw = hxb + (size_t)((t + 1) & 1) * (BATCH * HDIM);
    #pragma unroll
    for (int r = 0; r < 4; ++r) {
      float x0 = t0[r], x1 = t1[r];
      float y0 = 1.f / (1.f + __expf(-x0));
      float s1 = (n < 8) ? 2.f * x1 : x1;
      float sg1 = 1.f / (1.f + __expf(-s1));
      float y1 = (n < 8) ? (2.f * sg1 - 1.f) : sg1;
      float iv = __shfl(y0, l | 8, 64);              // i-gate, same h-col
      float ov = __shfl(y1, l | 8, 64);              // o-gate, same h-col
      float c = y0 * cx[r] + iv * y1;                // valid on n<8 lanes
      cx[r] = c;
      float th = 2.f / (1.f + __expf(-2.f * c)) - 1.f;
      float hv = ov * th;

      // gather the wave's 8 h-cols into lane n==0 (per lg)
      float h1 = __shfl(hv, (l & 48) | 1, 64);
      float h2 = __shfl(hv, (l & 48) | 2, 64);
      float h3 = __shfl(hv, (l & 48) | 3, 64);
      float h4 = __shfl(hv, (l & 48) | 4, 64);
      float h5 = __shfl(hv, (l & 48) | 5, 64);
      float h6 = __shfl(hv, (l & 48) | 6, 64);
      float h7 = __shfl(hv, (l & 48) | 7, 64);

      if (n == 0 && lg < 2) {
        int ba = g * 8 + lg * 4 + r;
        union { u32 u[4]; f32x4 v; } pk;
        pk.u[0] = (u32)f2bf(hv) | ((u32)f2bf(h1) << 16);
        pk.u[1] = (u32)f2bf(h2) | ((u32)f2bf(h3) << 16);
        pk.u[2] = (u32)f2bf(h4) | ((u32)f2bf(h5) << 16);
        pk.u[3] = (u32)f2bf(h6) | ((u32)f2bf(h7) << 16);
        u16* dst = hw + (size_t)ba * HDIM + h0w;
        if (PURE)
          asm volatile("global_store_dwordx4 %0, %1, off sc0"
                       :: "v"(dst), "v"(pk.v) : "memory");
        else
          asm volatile("global_store_dwordx4 %0, %1, off sc0 sc1"
                       :: "v"(dst), "v"(pk.v) : "memory");
        float4 oa = {hv, h1, h2, h3};
        float4 ob = {h4, h5, h6, h7};
        float* op = out + ((size_t)t * BATCH + ba) * HDIM + h0w;
        *reinterpret_cast<float4*>(op)     = oa;
        *reinterpret_cast<float4*>(op + 4) = ob;
        if (t == T_STEPS - 1) {
          float* hp = out + (size_t)T_STEPS * BATCH * HDIM + (size_t)ba * HDIM + h0w;
          *reinterpret_cast<float4*>(hp)     = oa;
          *reinterpret_cast<float4*>(hp + 4) = ob;
        }
      }
      if (t == T_STEPS - 1) {
        float q1 = __shfl(c, (l & 48) | 1, 64);
        float q2 = __shfl(c, (l & 48) | 2, 64);
        float q3 = __shfl(c, (l & 48) | 3, 64);
        float q4 = __shfl(c, (l & 48) | 4, 64);
        float q5 = __shfl(c, (l & 48) | 5, 64);
        float q6 = __shfl(c, (l & 48) | 6, 64);
        float q7 = __shfl(c, (l & 48) | 7, 64);
        if (n == 0 && lg < 2) {
          int ba = g * 8 + lg * 4 + r;
          float* cp = out + (size_t)T_STEPS * BATCH * HDIM + (size_t)BATCH * HDIM
                    + (size_t)ba * HDIM + h0w;
          float4 ca = {c, q1, q2, q3};
          float4 cb = {q4, q5, q6, q7};
          *reinterpret_cast<float4*>(cp)     = ca;
          *reinterpret_cast<float4*>(cp + 4) = cb;
        }
      }
    }

    // drain stores (L2 ack on PURE path), then arrive
    asm volatile("s_waitcnt vmcnt(0)" ::: "memory");
    __builtin_amdgcn_sched_barrier(0);
    __syncthreads();
    if (tid == 0) {
      u32 fv = (u32)(t + 1);
      u32* fp = flags + (g * NSHARD + j) * 16;
      if (PURE) {
        // fast copy for same-L2 pollers + device-scope copy (escalation net)
        asm volatile("global_store_dword %0, %1, off sc0"
                     :: "v"(fp), "v"(fv) : "memory");
        asm volatile("global_store_dword %0, %1, off sc0 sc1"
                     :: "v"(fp), "v"(fv) : "memory");
      } else {
        __hip_atomic_store(fp, fv, __ATOMIC_RELAXED, __HIP_MEMORY_SCOPE_AGENT);
      }
    }
  }
}

__launch_bounds__(256, 1)
__global__ void k_lstm(const u16* __restrict__ Gb,    // [32768][4096] bf16
                       const float* __restrict__ W,   // [4096][1536] fp32
                       u16* __restrict__ hxb,         // [2][64][1024] bf16
                       u32* __restrict__ arr,         // 256 x 16 u32 flags + ctrl
                       float* __restrict__ out) {
  __shared__ f32x4 As[2048];   // 32 KB: A fragments [ks][lg][row] (16B slots)
  __shared__ u32 pureSh;
  const int tid = threadIdx.x;
  const int w = blockIdx.x;
  const int g = w & 7;                           // batch group: rows [8g, 8g+8)
  const int j = w >> 3;                          // h-shard: h [32j, 32j+32)
  const int wv = tid >> 6, l = tid & 63;
  const int n = l & 15, lg = l >> 4;
  const int h0w = j * 32 + wv * 8;
  const int jcol0 = (n >> 3) * HDIM + h0w + (n & 7);        // f / i gate rows
  const int jcol1 = (2 + (n >> 3)) * HDIM + h0w + (n & 7);  // g / o gate rows

  // --- report XCD; purity decided later on full evidence only ---
  u32 xcd;
  asm volatile("s_getreg_b32 %0, hwreg(HW_REG_XCC_ID)" : "=s"(xcd));
  u32* mask = arr + 8192;      // 8 u32, one per group
  u32* done = arr + 8200;      // arrival counter
  if (tid == 0) {
    __hip_atomic_fetch_or(&mask[g], 1u << (xcd & 7u),
                          __ATOMIC_RELAXED, __HIP_MEMORY_SCOPE_AGENT);
    __hip_atomic_fetch_add(done, 1u, __ATOMIC_RELEASE, __HIP_MEMORY_SCOPE_AGENT);
  }

  // --- preload W_h fragments into registers (overlaps rendezvous): 256 VGPR ---
  bf16x8 w0[32], w1[32];
  #pragma unroll
  for (int ks = 0; ks < 32; ++ks) {
    const float* wp = W + (size_t)jcol0 * KDIM + IDIM + ks * 32 + lg * 8;
    float4 v0 = *reinterpret_cast<const float4*>(wp);
    float4 v1 = *reinterpret_cast<const float4*>(wp + 4);
    bf16x8 fr;
    fr[0] = (short)f2bf(v0.x); fr[1] = (short)f2bf(v0.y);
    fr[2] = (short)f2bf(v0.z); fr[3] = (short)f2bf(v0.w);
    fr[4] = (short)f2bf(v1.x); fr[5] = (short)f2bf(v1.y);
    fr[6] = (short)f2bf(v1.z); fr[7] = (short)f2bf(v1.w);
    w0[ks] = fr;
  }
  #pragma unroll
  for (int ks = 0; ks < 32; ++ks) {
    const float* wp = W + (size_t)jcol1 * KDIM + IDIM + ks * 32 + lg * 8;
    float4 v0 = *reinterpret_cast<const float4*>(wp);
    float4 v1 = *reinterpret_cast<const float4*>(wp + 4);
    bf16x8 fr;
    fr[0] = (short)f2bf(v0.x); fr[1] = (short)f2bf(v0.y);
    fr[2] = (short)f2bf(v0.z); fr[3] = (short)f2bf(v0.w);
    fr[4] = (short)f2bf(v1.x); fr[5] = (short)f2bf(v1.y);
    fr[6] = (short)f2bf(v1.z); fr[7] = (short)f2bf(v1.w);
    w1[ks] = fr;
  }

  // zero LDS once: pad rows (slot&15 >= 8) must read as 0 every step
  #pragma unroll
  for (int i = 0; i < 8; ++i)
    As[i * 256 + tid] = (f32x4){0.f, 0.f, 0.f, 0.f};

  // --- BOUNDED rendezvous: timeout => impure => proven slow path (no hang) ---
  if (tid == 0) {
    u32 it = 0, ok = 0;
    while (it++ < (1u << 17)) {
      if (__hip_atomic_load(done, __ATOMIC_ACQUIRE, __HIP_MEMORY_SCOPE_AGENT)
          >= (u32)NWG) { ok = 1u; break; }
      __builtin_amdgcn_s_sleep(2);
    }
    u32 m = ok ? __hip_atomic_load(&mask[g], __ATOMIC_RELAXED,
                                   __HIP_MEMORY_SCOPE_AGENT)
               : 3u;   // pretend 2 XCDs -> impure
    pureSh = (__popc(m) == 1) ? 1u : 0u;
  }
  __syncthreads();

  if (pureSh) lstm_run<true >(Gb, hxb, arr, out, As, w0, w1, g, j, tid, jcol0, jcol1);
  else        lstm_run<false>(Gb, hxb, arr, out, As, w0, w1, g, j, tid, jcol0, jcol1);
}

// ---------------- launch ----------------
extern "C" void kernel_launch(void* const* d_in, const int* in_sizes, int n_in,
                              void* d_out, int out_size, void* d_ws, size_t ws_size,
                              hipStream_t stream) {
  const float* x  = (const float*)d_in[0];   // [512][64][512]
  const float* W  = (const float*)d_in[1];   // [4096][1536]
  const float* b  = (const float*)d_in[2];   // [4096]
  float* out = (float*)d_out;
  char* ws = (char*)d_ws;

  u16* Gb  = (u16*)(ws + GB_OFF);
  u16* Xb  = (u16*)(ws + XB_OFF);
  u16* Wxb = (u16*)(ws + WX_OFF);
  u16* hxb = (u16*)(ws + HX_OFF);
  u32* arr = (u32*)(ws + ARR_OFF);

  // A: convert X and Wx to bf16, zero hx buffers
  k_cvt4<<<2048, 256, 0, stream>>>(x, Xb, (T_STEPS * BATCH * IDIM) / 4);
  k_cvt_wx<<<(GDIM * (IDIM / 4) + 255) / 256, 256, 0, stream>>>(W, Wxb);
  k_zero<<<256, 256, 0, stream>>>((u32*)hxb, (2 * BATCH * HDIM * 2) / 4);

  // B: Gx = X @ Wx^T + b  (consumes Xb; Xb region is dead afterwards)
  dim3 gB(256, 32);
  k_gemm_gx<<<gB, 256, 0, stream>>>(Xb, Wxb, b, Gb);

  // zero barrier flags + rendezvous ctrl (overlaid on dead Xb region)
  k_zero<<<33, 256, 0, stream>>>((u32*)(ws + ARR_OFF), 8208);

  // C: persistent recurrent kernel
  k_lstm<<<NWG, 256, 0, stream>>>(Gb, (const float*)W, hxb, arr, out);
}

// Round 3
// 3060.531 us; speedup vs baseline: 46.6181x; 46.6181x over previous
//
#include <hip/hip_runtime.h>
#include <stdint.h>

typedef unsigned int u32;
typedef unsigned long long u64;
typedef unsigned short u16;
typedef __attribute__((ext_vector_type(8))) short bf16x8;
typedef __attribute__((ext_vector_type(4))) float f32x4;
typedef __attribute__((ext_vector_type(4))) u16 u16x4;

// Problem constants
#define T_STEPS 512
#define BATCH   64
#define IDIM    512
#define HDIM    1024
#define GDIM    4096   // 4*H
#define KDIM    1536   // I+H
#define NWG     256    // 8 batch-groups x 32 h-shards, 1 WG/CU (proven chassis)

// ws layout (bytes)
#define GB_OFF  0u                    // Gx bf16 [32768][4096]  = 268435456
#define XB_OFF  268435456u            // X bf16  [32768][512]   = 33554432
#define WX_OFF  301989888u            // Wx bf16 [4096][512]    = 4194304 (dead after gemm)
// hseq (tagged h exchange) overlays the dead Wx region after k_gemm_gx:
// u32 [2][64][1024] = 524288 bytes
#define HSEQ_OFF WX_OFF

__device__ __forceinline__ u16 f2bf(float f) {
  union { float f; u32 u; } v; v.f = f;
  return (u16)((v.u + 0x7fffu + ((v.u >> 16) & 1u)) >> 16);   // RNE
}
__device__ __forceinline__ float bf2f(u16 h) {
  union { u32 u; float f; } v; v.u = ((u32)h) << 16; return v.f;
}
__device__ __forceinline__ u32 FU(float f) {
  union { float f; u32 u; } v; v.f = f; return v.u;
}
__device__ __forceinline__ float UF(u32 u) {
  union { u32 u; float f; } v; v.u = u; return v.f;
}

#define GLDS(g, l) __builtin_amdgcn_global_load_lds( \
    (const __attribute__((address_space(1))) u32*)(g), \
    (__attribute__((address_space(3))) u32*)(l), 16, 0, 0)

// ---------------- Phase A: conversions / init ----------------
__global__ void k_cvt4(const float* __restrict__ src, u16* __restrict__ dst, int n4) {
  int i = blockIdx.x * blockDim.x + threadIdx.x;
  int stride = gridDim.x * blockDim.x;
  for (; i < n4; i += stride) {
    float4 v = reinterpret_cast<const float4*>(src)[i];
    u16x4 o; o.x = f2bf(v.x); o.y = f2bf(v.y); o.z = f2bf(v.z); o.w = f2bf(v.w);
    reinterpret_cast<u16x4*>(dst)[i] = o;
  }
}

__global__ void k_cvt_wx(const float* __restrict__ W, u16* __restrict__ wxb) {
  int i = blockIdx.x * blockDim.x + threadIdx.x;   // over 4096*128 float4 groups
  if (i >= GDIM * (IDIM / 4)) return;
  int row = i >> 7, cg = i & 127;
  float4 v = *reinterpret_cast<const float4*>(W + (size_t)row * KDIM + cg * 4);
  u16x4 o; o.x = f2bf(v.x); o.y = f2bf(v.y); o.z = f2bf(v.z); o.w = f2bf(v.w);
  *reinterpret_cast<u16x4*>(wxb + (size_t)row * IDIM + cg * 4) = o;
}

__global__ void k_zero(u32* __restrict__ p, int n) {
  int i = blockIdx.x * blockDim.x + threadIdx.x;
  int stride = gridDim.x * blockDim.x;
  for (; i < n; i += stride) p[i] = 0u;
}

// ---------------- Phase B: Gx = Xbf16 @ Wx^T + b (bf16 out) ----------------
// M=32768, N=4096, K=512. 128x128 tile, BK=64, 4 waves each 64x64.
__global__ void k_gemm_gx(const u16* __restrict__ Xb, const u16* __restrict__ Wxb,
                          const float* __restrict__ bias, u16* __restrict__ Gb) {
  __shared__ u16 lA[128 * 64];
  __shared__ u16 lB[128 * 64];
  const int tid = threadIdx.x;
  const int wv = tid >> 6, l = tid & 63;
  const int ln = l & 15, lg = l >> 4;
  const int m0 = blockIdx.x * 128, n0 = blockIdx.y * 128;
  const int wr = wv >> 1, wc = wv & 1;

  f32x4 acc[4][4];
  #pragma unroll
  for (int mi = 0; mi < 4; ++mi)
    #pragma unroll
    for (int nj = 0; nj < 4; ++nj) acc[mi][nj] = (f32x4){0.f, 0.f, 0.f, 0.f};

  for (int kt = 0; kt < 8; ++kt) {
    #pragma unroll
    for (int it = 0; it < 4; ++it) {
      int off = it * 4096 + tid * 16;      // byte offset in 16KB tile
      int row = off >> 7;                  // 128 B per row (64 bf16)
      int col = (off & 127) >> 1;          // bf16 col
      GLDS(Xb  + (size_t)(m0 + row) * IDIM + kt * 64 + col, (char*)lA + off);
      GLDS(Wxb + (size_t)(n0 + row) * IDIM + kt * 64 + col, (char*)lB + off);
    }
    asm volatile("s_waitcnt vmcnt(0)" ::: "memory");
    __syncthreads();
    #pragma unroll
    for (int ks = 0; ks < 2; ++ks) {
      bf16x8 af[4], bfr[4];
      #pragma unroll
      for (int mi = 0; mi < 4; ++mi)
        af[mi] = *reinterpret_cast<const bf16x8*>(&lA[(wr * 64 + mi * 16 + ln) * 64 + ks * 32 + lg * 8]);
      #pragma unroll
      for (int nj = 0; nj < 4; ++nj)
        bfr[nj] = *reinterpret_cast<const bf16x8*>(&lB[(wc * 64 + nj * 16 + ln) * 64 + ks * 32 + lg * 8]);
      #pragma unroll
      for (int mi = 0; mi < 4; ++mi)
        #pragma unroll
        for (int nj = 0; nj < 4; ++nj)
          acc[mi][nj] = __builtin_amdgcn_mfma_f32_16x16x32_bf16(af[mi], bfr[nj], acc[mi][nj], 0, 0, 0);
    }
    __syncthreads();
  }
  float bv[4];
  #pragma unroll
  for (int nj = 0; nj < 4; ++nj) bv[nj] = bias[n0 + wc * 64 + nj * 16 + ln];
  #pragma unroll
  for (int mi = 0; mi < 4; ++mi)
    #pragma unroll
    for (int r = 0; r < 4; ++r) {
      int m = m0 + wr * 64 + mi * 16 + lg * 4 + r;
      #pragma unroll
      for (int nj = 0; nj < 4; ++nj)
        Gb[(size_t)m * GDIM + n0 + wc * 64 + nj * 16 + ln] = f2bf(acc[mi][nj][r] + bv[nj]);
    }
}

// ---------------- Phase C: persistent recurrent kernel ----------------
// 256 WGs = 8 batch-groups(g = w&7: 8 rows) x 32 h-shards(j = w>>3: 32 h),
// 1 WG/CU. NO separate barrier: h is exchanged as TAGGED u32 words
// (tag<<16 | bf16), stored as 16B chunks (single dwordx4 = indivisible, so
// tag+payload within a chunk are consistent). Readers poll their staging
// loads directly, accepting a chunk iff all 4 tags == t. Double-buffered
// over t&1 (overwrite happens-after consumption by the 2-phase argument).
// Deletes: flag store, flag poll, pre-flag vmcnt drain (the poll's own
// vmcnt(0) drains prior stores). All device-scope (sc0 sc1).
__launch_bounds__(256, 1)
__global__ void k_lstm(const u16* __restrict__ Gb,    // [32768][4096] bf16
                       const float* __restrict__ W,   // [4096][1536] fp32
                       u32* __restrict__ hseq,        // [2][64][1024] tagged u32
                       float* __restrict__ out) {
  __shared__ f32x4 As[2048];   // 32 KB: A fragments [ks][lg][row] (16B slots)
  const int tid = threadIdx.x;
  const int w = blockIdx.x;
  const int g = w & 7;                           // batch group: rows [8g, 8g+8)
  const int j = w >> 3;                          // h-shard: h [32j, 32j+32)
  const int wv = tid >> 6, l = tid & 63;
  const int n = l & 15, lg = l >> 4;
  const int h0w = j * 32 + wv * 8;               // this wave's 8 h-cols
  const int jcol0 = (n >> 3) * HDIM + h0w + (n & 7);        // f / i gate rows
  const int jcol1 = (2 + (n >> 3)) * HDIM + h0w + (n & 7);  // g / o gate rows
  const int srow = tid & 7, sseg = tid >> 3;     // staging: 8 rows x 32 segs(32 cols)

  // --- preload W_h fragments into registers (once): 2 x 32 x bf16x8 ---
  bf16x8 w0[32], w1[32];
  #pragma unroll
  for (int ks = 0; ks < 32; ++ks) {
    const float* wp = W + (size_t)jcol0 * KDIM + IDIM + ks * 32 + lg * 8;
    float4 v0 = *reinterpret_cast<const float4*>(wp);
    float4 v1 = *reinterpret_cast<const float4*>(wp + 4);
    bf16x8 fr;
    fr[0] = (short)f2bf(v0.x); fr[1] = (short)f2bf(v0.y);
    fr[2] = (short)f2bf(v0.z); fr[3] = (short)f2bf(v0.w);
    fr[4] = (short)f2bf(v1.x); fr[5] = (short)f2bf(v1.y);
    fr[6] = (short)f2bf(v1.z); fr[7] = (short)f2bf(v1.w);
    w0[ks] = fr;
  }
  #pragma unroll
  for (int ks = 0; ks < 32; ++ks) {
    const float* wp = W + (size_t)jcol1 * KDIM + IDIM + ks * 32 + lg * 8;
    float4 v0 = *reinterpret_cast<const float4*>(wp);
    float4 v1 = *reinterpret_cast<const float4*>(wp + 4);
    bf16x8 fr;
    fr[0] = (short)f2bf(v0.x); fr[1] = (short)f2bf(v0.y);
    fr[2] = (short)f2bf(v0.z); fr[3] = (short)f2bf(v0.w);
    fr[4] = (short)f2bf(v1.x); fr[5] = (short)f2bf(v1.y);
    fr[6] = (short)f2bf(v1.z); fr[7] = (short)f2bf(v1.w);
    w1[ks] = fr;
  }

  // zero LDS once: pad rows (slot&15 >= 8) must read as 0 every step
  #pragma unroll
  for (int i = 0; i < 8; ++i)
    As[i * 256 + tid] = (f32x4){0.f, 0.f, 0.f, 0.f};
  __syncthreads();

  float cx[4] = {0.f, 0.f, 0.f, 0.f};

  #pragma unroll 1
  for (int t = 0; t < T_STEPS; ++t) {
    // issue Gx loads early (plain loads; latency hides under the data poll)
    u16 ga[4] = {0, 0, 0, 0}, gb_[4] = {0, 0, 0, 0};
    if (lg < 2) {
      #pragma unroll
      for (int r = 0; r < 4; ++r) {
        int ba = g * 8 + lg * 4 + r;
        const u16* gp = Gb + ((size_t)t * BATCH + ba) * GDIM;
        ga[r]  = gp[jcol0];
        gb_[r] = gp[jcol1];
      }
    }

    // ---- data-is-the-flag staging poll ----
    // thread (srow, sseg) owns hseq[t&1][8g+srow][sseg*32 .. +32) = 8 chunks.
    // Accept chunk iff all 4 tags == t. vmcnt(0) here also drains our own
    // h-stores from the previous step (release side of the protocol).
    const u32* psrc = hseq + (size_t)(t & 1) * (BATCH * HDIM)
                    + (size_t)(g * 8 + srow) * HDIM + sseg * 32;
    const u32 tt = (u32)t << 16;
    f32x4 ld[8];
    u32 need = 0xffu, spin = 0;
    while (true) {
      #pragma unroll
      for (int q = 0; q < 8; ++q)
        if (need & (1u << q))
          asm volatile("global_load_dwordx4 %0, %1, off sc0 sc1"
                       : "=&v"(ld[q]) : "v"(psrc + q * 4) : "memory");
      asm volatile("s_waitcnt vmcnt(0)" ::: "memory");
      __builtin_amdgcn_sched_barrier(0);
      u32 bad = 0;
      #pragma unroll
      for (int q = 0; q < 8; ++q)
        if (need & (1u << q)) {
          u32 m = ((FU(ld[q].x) ^ tt) | (FU(ld[q].y) ^ tt)
                 | (FU(ld[q].z) ^ tt) | (FU(ld[q].w) ^ tt)) & 0xffff0000u;
          if (m) bad |= (1u << q);
        }
      need = bad;
      if (!__any((int)need)) break;        // wave-uniform exit
      if (++spin > (1u << 20)) break;      // safety: terminate, fail visibly
    }

    // pack low16 (bf16 payload) into MFMA fragment slots in LDS
    #pragma unroll
    for (int qq = 0; qq < 4; ++qq) {
      u32 a0 = FU(ld[2 * qq + 0].x), a1 = FU(ld[2 * qq + 0].y);
      u32 a2 = FU(ld[2 * qq + 0].z), a3 = FU(ld[2 * qq + 0].w);
      u32 b0 = FU(ld[2 * qq + 1].x), b1 = FU(ld[2 * qq + 1].y);
      u32 b2 = FU(ld[2 * qq + 1].z), b3 = FU(ld[2 * qq + 1].w);
      f32x4 s;
      s[0] = UF((a0 & 0xffffu) | (a1 << 16));
      s[1] = UF((a2 & 0xffffu) | (a3 << 16));
      s[2] = UF((b0 & 0xffffu) | (b1 << 16));
      s[3] = UF((b2 & 0xffffu) | (b3 << 16));
      As[sseg * 64 + qq * 16 + srow] = s;   // As[ks][lg][row]
    }
    __syncthreads();

    // gates = Gx + hx @ Wh^T : 2 N-tiles x 32 ks, 4 independent MFMA chains
    f32x4 c00 = {bf2f(ga[0]),  bf2f(ga[1]),  bf2f(ga[2]),  bf2f(ga[3])};
    f32x4 c10 = {bf2f(gb_[0]), bf2f(gb_[1]), bf2f(gb_[2]), bf2f(gb_[3])};
    f32x4 c01 = {0.f, 0.f, 0.f, 0.f}, c11 = c01;
    #pragma unroll
    for (int ks = 0; ks < 32; ks += 2) {
      bf16x8 f0 = *reinterpret_cast<const bf16x8*>(&As[(ks + 0) * 64 + l]);
      bf16x8 f1 = *reinterpret_cast<const bf16x8*>(&As[(ks + 1) * 64 + l]);
      c00 = __builtin_amdgcn_mfma_f32_16x16x32_bf16(f0, w0[ks + 0], c00, 0, 0, 0);
      c10 = __builtin_amdgcn_mfma_f32_16x16x32_bf16(f0, w1[ks + 0], c10, 0, 0, 0);
      c01 = __builtin_amdgcn_mfma_f32_16x16x32_bf16(f1, w0[ks + 1], c01, 0, 0, 0);
      c11 = __builtin_amdgcn_mfma_f32_16x16x32_bf16(f1, w1[ks + 1], c11, 0, 0, 0);
    }
    f32x4 t0 = c00 + c01, t1 = c10 + c11;

    // elementwise. tile0: n<8 -> f, n>=8 -> i. tile1: n<8 -> g(tanh), n>=8 -> o.
    const u32 tg = ((u32)(t + 1)) << 16;
    u32* hwq = hseq + (size_t)((t + 1) & 1) * (BATCH * HDIM);
    #pragma unroll
    for (int r = 0; r < 4; ++r) {
      float x0 = t0[r], x1 = t1[r];
      float y0 = 1.f / (1.f + __expf(-x0));
      float s1 = (n < 8) ? 2.f * x1 : x1;
      float sg1 = 1.f / (1.f + __expf(-s1));
      float y1 = (n < 8) ? (2.f * sg1 - 1.f) : sg1;
      float iv = __shfl(y0, l | 8, 64);              // i-gate, same h-col
      float ov = __shfl(y1, l | 8, 64);              // o-gate, same h-col
      float c = y0 * cx[r] + iv * y1;                // valid on n<8 lanes
      cx[r] = c;
      float th = 2.f / (1.f + __expf(-2.f * c)) - 1.f;
      float hv = ov * th;

      // gather the wave's 8 h-cols into lane n==0 (per lg)
      float h1 = __shfl(hv, (l & 48) | 1, 64);
      float h2 = __shfl(hv, (l & 48) | 2, 64);
      float h3 = __shfl(hv, (l & 48) | 3, 64);
      float h4 = __shfl(hv, (l & 48) | 4, 64);
      float h5 = __shfl(hv, (l & 48) | 5, 64);
      float h6 = __shfl(hv, (l & 48) | 6, 64);
      float h7 = __shfl(hv, (l & 48) | 7, 64);

      if (n == 0 && lg < 2) {
        int ba = g * 8 + lg * 4 + r;
        union { u32 u[4]; f32x4 v; } pa, pb;
        pa.u[0] = tg | f2bf(hv); pa.u[1] = tg | f2bf(h1);
        pa.u[2] = tg | f2bf(h2); pa.u[3] = tg | f2bf(h3);
        pb.u[0] = tg | f2bf(h4); pb.u[1] = tg | f2bf(h5);
        pb.u[2] = tg | f2bf(h6); pb.u[3] = tg | f2bf(h7);
        u32* dst = hwq + (size_t)ba * HDIM + h0w;
        asm volatile("global_store_dwordx4 %0, %1, off sc0 sc1"
                     :: "v"(dst), "v"(pa.v) : "memory");
        asm volatile("global_store_dwordx4 %0, %1, off sc0 sc1"
                     :: "v"(dst + 4), "v"(pb.v) : "memory");
        float4 oa = {hv, h1, h2, h3};
        float4 ob = {h4, h5, h6, h7};
        float* op = out + ((size_t)t * BATCH + ba) * HDIM + h0w;
        *reinterpret_cast<float4*>(op)     = oa;
        *reinterpret_cast<float4*>(op + 4) = ob;
        if (t == T_STEPS - 1) {
          float* hp = out + (size_t)T_STEPS * BATCH * HDIM + (size_t)ba * HDIM + h0w;
          *reinterpret_cast<float4*>(hp)     = oa;
          *reinterpret_cast<float4*>(hp + 4) = ob;
        }
      }
      if (t == T_STEPS - 1) {
        float q1 = __shfl(c, (l & 48) | 1, 64);
        float q2 = __shfl(c, (l & 48) | 2, 64);
        float q3 = __shfl(c, (l & 48) | 3, 64);
        float q4 = __shfl(c, (l & 48) | 4, 64);
        float q5 = __shfl(c, (l & 48) | 5, 64);
        float q6 = __shfl(c, (l & 48) | 6, 64);
        float q7 = __shfl(c, (l & 48) | 7, 64);
        if (n == 0 && lg < 2) {
          int ba = g * 8 + lg * 4 + r;
          float* cp = out + (size_t)T_STEPS * BATCH * HDIM + (size_t)BATCH * HDIM
                    + (size_t)ba * HDIM + h0w;
          float4 ca = {c, q1, q2, q3};
          float4 cb = {q4, q5, q6, q7};
          *reinterpret_cast<float4*>(cp)     = ca;
          *reinterpret_cast<float4*>(cp + 4) = cb;
        }
      }
    }

    // LDS reuse fence: all MFMA reads of As done before next step's staging
    __syncthreads();
  }
}

// ---------------- launch ----------------
extern "C" void kernel_launch(void* const* d_in, const int* in_sizes, int n_in,
                              void* d_out, int out_size, void* d_ws, size_t ws_size,
                              hipStream_t stream) {
  const float* x  = (const float*)d_in[0];   // [512][64][512]
  const float* W  = (const float*)d_in[1];   // [4096][1536]
  const float* b  = (const float*)d_in[2];   // [4096]
  float* out = (float*)d_out;
  char* ws = (char*)d_ws;

  u16* Gb   = (u16*)(ws + GB_OFF);
  u16* Xb   = (u16*)(ws + XB_OFF);
  u16* Wxb  = (u16*)(ws + WX_OFF);
  u32* hseq = (u32*)(ws + HSEQ_OFF);

  // A: convert X and Wx to bf16
  k_cvt4<<<2048, 256, 0, stream>>>(x, Xb, (T_STEPS * BATCH * IDIM) / 4);
  k_cvt_wx<<<(GDIM * (IDIM / 4) + 255) / 256, 256, 0, stream>>>(W, Wxb);

  // B: Gx = X @ Wx^T + b  (consumes Xb and Wxb; both dead afterwards)
  dim3 gB(256, 32);
  k_gemm_gx<<<gB, 256, 0, stream>>>(Xb, Wxb, b, Gb);

  // zero tagged h-exchange buffer (overlaid on dead Wx region) after the GEMM
  k_zero<<<512, 256, 0, stream>>>(hseq, 2 * BATCH * HDIM);

  // C: persistent recurrent kernel
  k_lstm<<<NWG, 256, 0, stream>>>(Gb, (const float*)W, hseq, out);
}